// Round 6
// baseline (8443.916 us; speedup 1.0000x reference)
//
#include <hip/hip_runtime.h>
#include <hip/hip_bf16.h>
#include <math.h>

namespace {

constexpr int Bn = 8;
constexpr int Nn = 729;
constexpr int Cn = 1152;
constexpr int Hn = 16;
constexpr int Dn = 72;
constexpr int Fn = 4304;
constexpr int Rn = 23;
constexpr int NAn = 365;              // even tokens (src half)
constexpr int NBn = 364;              // odd tokens (dst half)
constexpr int NMn = 706;              // N - R merged tokens
constexpr int UNMn = NAn - Rn;        // 342 unmerged
constexpr float EPSf = 1e-6f;
constexpr float SCALEf = 0.11785113019775793f;  // 72^-0.5

__device__ __forceinline__ float geluf(float x) {
  float x3 = x * x * x;
  return 0.5f * x * (1.f + tanhf(0.7978845608028654f * (x + 0.044715f * x3)));
}

__device__ __forceinline__ int clampi(int v, int lo, int hi) {
  return v < lo ? lo : (v > hi ? hi : v);
}

// -------- LN stats: one block per row; writes fp32 (value path) + fp64 (decision path) --------
__global__ __launch_bounds__(256) void ln_stats_kernel(const float* __restrict__ x,
                                                       float* __restrict__ sf,
                                                       double* __restrict__ sd,
                                                       int rows) {
  int row = blockIdx.x;
  if (row >= rows) return;
  const float* xr = x + (size_t)row * Cn;
  double s = 0.0, s2 = 0.0;
  for (int c = threadIdx.x; c < Cn; c += 256) {
    double v = (double)xr[c];
    s += v; s2 += v * v;
  }
  __shared__ double sh[8];
#pragma unroll
  for (int o = 32; o > 0; o >>= 1) { s += __shfl_down(s, o); s2 += __shfl_down(s2, o); }
  int w = threadIdx.x >> 6;
  if ((threadIdx.x & 63) == 0) { sh[w] = s; sh[4 + w] = s2; }
  __syncthreads();
  if (threadIdx.x == 0) {
    double ts = sh[0] + sh[1] + sh[2] + sh[3];
    double ts2 = sh[4] + sh[5] + sh[6] + sh[7];
    double mean = ts / Cn;
    double var = ts2 / Cn - mean * mean;
    double rstd = 1.0 / sqrt(var + (double)EPSf);
    sf[2 * row] = (float)mean;
    sf[2 * row + 1] = (float)rstd;
    if (sd) { sd[2 * row] = mean; sd[2 * row + 1] = rstd; }
  }
}

// -------- Decision path: wk_avg[c][d] = mean_h wk[c][h*D+d], bk_avg likewise (fp64) --------
__global__ __launch_bounds__(128) void wkavg_kernel(const float* __restrict__ wk,
                                                    const float* __restrict__ bk,
                                                    double* __restrict__ wka,
                                                    double* __restrict__ bka) {
  int c = blockIdx.x;
  int d = threadIdx.x;
  if (d < Dn) {
    double s = 0.0;
    for (int h = 0; h < Hn; ++h) s += (double)wk[(size_t)c * Cn + h * Dn + d];
    wka[(size_t)c * Dn + d] = s / Hn;
    if (c == 0) {
      double t = 0.0;
      for (int h = 0; h < Hn; ++h) t += (double)bk[h * Dn + d];
      bka[d] = t / Hn;
    }
  }
}

// -------- Decision path: metric[row] = normalize( LN1(x_row) @ wk_avg + bk_avg ), fp64 --------
__global__ __launch_bounds__(128) void metric_d_kernel(const float* __restrict__ x,
                                                       const double* __restrict__ sd,
                                                       const float* __restrict__ g,
                                                       const float* __restrict__ b,
                                                       const double* __restrict__ wka,
                                                       const double* __restrict__ bka,
                                                       double* __restrict__ mn) {
  int row = blockIdx.x;  // b*N + n
  __shared__ double as_[Cn];
  __shared__ double red[Dn];
  __shared__ double nrm;
  double mean = sd[2 * row], rstd = sd[2 * row + 1];
  const float* xr = x + (size_t)row * Cn;
  for (int c = threadIdx.x; c < Cn; c += 128)
    as_[c] = ((double)xr[c] - mean) * rstd * (double)g[c] + (double)b[c];
  __syncthreads();
  int d = threadIdx.x;
  double acc = 0.0;
  if (d < Dn) {
    for (int c = 0; c < Cn; ++c) acc += as_[c] * wka[(size_t)c * Dn + d];
    acc += bka[d];
    red[d] = acc * acc;
  }
  __syncthreads();
  if (threadIdx.x == 0) {
    double t = 0.0;
    for (int i = 0; i < Dn; ++i) t += red[i];
    nrm = 1.0 / sqrt(t > 0.0 ? t : 1e-300);
  }
  __syncthreads();
  if (d < Dn) mn[(size_t)row * Dn + d] = acc * nrm;
}

// -------- Decision path: per-src max similarity + argmax (first occurrence), fp64 --------
__global__ __launch_bounds__(128) void tome_score_kernel(const double* __restrict__ mn,
                                                         double* __restrict__ nmax,
                                                         int* __restrict__ nidx) {
  int blk = blockIdx.x;
  int i = blk % NAn;
  int b = blk / NAn;
  __shared__ double av[Dn];
  __shared__ double sv[128];
  __shared__ int si[128];
  int tid = threadIdx.x;
  if (tid < Dn) av[tid] = mn[((size_t)(b * Nn) + 2 * i) * Dn + tid];
  __syncthreads();
  double best = -1e300;
  int bi = 0;
  for (int c2 = tid; c2 < NBn; c2 += 128) {
    const double* bv = mn + ((size_t)(b * Nn) + 2 * c2 + 1) * Dn;
    double s = 0.0;
#pragma unroll 8
    for (int dd = 0; dd < Dn; ++dd) s += av[dd] * bv[dd];
    if (s > best) { best = s; bi = c2; }  // strict > keeps first occurrence
  }
  sv[tid] = best;
  si[tid] = bi;
  __syncthreads();
  if (tid == 0) {
    double bb = sv[0];
    int ii = si[0];
    for (int t2 = 1; t2 < 128; ++t2) {
      if (sv[t2] > bb || (sv[t2] == bb && si[t2] < ii)) { bb = sv[t2]; ii = si[t2]; }
    }
    nmax[b * NAn + i] = bb;
    nidx[b * NAn + i] = clampi(ii, 0, NBn - 1);
  }
}

// -------- Decision path: stable descending argsort (rank-by-count), fp64 keys --------
__global__ __launch_bounds__(512) void tome_sort_kernel(const double* __restrict__ nmax,
                                                        const int* __restrict__ nidx,
                                                        int* __restrict__ unm,
                                                        int* __restrict__ srcI,
                                                        int* __restrict__ dstI,
                                                        float* __restrict__ cnt) {
  int b = blockIdx.x;
  __shared__ double v[NAn];
  __shared__ int eidx[NAn];
  __shared__ int dsts[Rn];
  int tid = threadIdx.x;
  for (int i = tid; i < NAn; i += blockDim.x) {
    v[i] = nmax[b * NAn + i];
    eidx[i] = i;  // defensive init
  }
  __syncthreads();
  for (int i = tid; i < NAn; i += blockDim.x) {
    double vi = v[i];
    int rank = 0;
    for (int j = 0; j < NAn; ++j) {
      double vj = v[j];
      rank += (vj > vi) || (vj == vi && j < i);  // stable descending
    }
    eidx[clampi(rank, 0, NAn - 1)] = i;
  }
  __syncthreads();
  for (int r2 = tid; r2 < NAn; r2 += blockDim.x) {
    if (r2 >= Rn) unm[(size_t)b * UNMn + (r2 - Rn)] = clampi(eidx[r2], 0, NAn - 1);
  }
  if (tid < Rn) {
    int s = clampi(eidx[tid], 0, NAn - 1);
    srcI[b * Rn + tid] = s;
    int dd = clampi(nidx[b * NAn + s], 0, NBn - 1);
    dsts[tid] = dd;
    dstI[b * Rn + tid] = dd;
  }
  for (int j = tid; j < NBn; j += blockDim.x) cnt[(size_t)b * NBn + j] = 1.f;
  __syncthreads();
  if (tid == 0) {
    for (int r2 = 0; r2 < Rn; ++r2) cnt[(size_t)b * NBn + dsts[r2]] += 1.f;
  }
}

// -------- Value path GEMM (fp32): C = LN?(A)[M,K] @ W[K,N] + bias (+gelu)(+resid) --------
constexpr int BM = 64, BN = 64, BK = 16;
__global__ __launch_bounds__(256) void gemm_kernel(const float* __restrict__ A,
                                                   const float* __restrict__ stats,
                                                   const float* __restrict__ lng,
                                                   const float* __restrict__ lnb,
                                                   const float* __restrict__ W,
                                                   const float* __restrict__ bias,
                                                   const float* __restrict__ resid,
                                                   float* __restrict__ Cout,
                                                   int M, int Nc, int K, int act) {
  __shared__ float As[BK][BM + 1];
  __shared__ float Bs[BK][BN + 1];
  int bm = blockIdx.y * BM, bn = blockIdx.x * BN;
  int tid = threadIdx.x;
  int tx = tid & 15, ty = tid >> 4;
  float acc[4][4] = {};
  for (int k0 = 0; k0 < K; k0 += BK) {
#pragma unroll
    for (int i = 0; i < 4; ++i) {   // A tile 64x16
      int idx = tid + i * 256;
      int m = idx >> 4;
      int kk = idx & 15;
      int gm = bm + m, gk = k0 + kk;
      float v = 0.f;
      if (gm < M) {
        v = A[(size_t)gm * K + gk];
        if (stats) v = (v - stats[2 * gm]) * stats[2 * gm + 1] * lng[gk] + lnb[gk];
      }
      As[kk][m] = v;
    }
#pragma unroll
    for (int i = 0; i < 4; ++i) {   // B tile 16x64
      int idx = tid + i * 256;
      int kk = idx >> 6;
      int n = idx & 63;
      float v = 0.f;
      if (bn + n < Nc) v = W[(size_t)(k0 + kk) * Nc + (bn + n)];
      Bs[kk][n] = v;
    }
    __syncthreads();
#pragma unroll
    for (int kk = 0; kk < BK; ++kk) {
      float a4[4], b4[4];
#pragma unroll
      for (int i = 0; i < 4; ++i) a4[i] = As[kk][ty * 4 + i];
#pragma unroll
      for (int j = 0; j < 4; ++j) b4[j] = Bs[kk][tx * 4 + j];
#pragma unroll
      for (int i = 0; i < 4; ++i)
#pragma unroll
        for (int j = 0; j < 4; ++j) acc[i][j] += a4[i] * b4[j];
    }
    __syncthreads();
  }
#pragma unroll
  for (int i = 0; i < 4; ++i) {
    int m = bm + ty * 4 + i;
    if (m >= M) continue;
#pragma unroll
    for (int j = 0; j < 4; ++j) {
      int n = bn + tx * 4 + j;
      if (n >= Nc) continue;
      float v = acc[i][j] + bias[n];
      if (act == 1) v = geluf(v);
      if (resid) v += resid[(size_t)m * Nc + n];
      Cout[(size_t)m * Nc + n] = v;
    }
  }
}

// -------- Flash attention (fp32); writes output IN-PLACE over q (disjoint slices) --------
constexpr int TQ = 16, TK = 64;
constexpr int NQT = (Nn + TQ - 1) / TQ;  // 46
__global__ __launch_bounds__(256) void attn_kernel(float* q /* in: q, out: attn */,
                                                   const float* __restrict__ k,
                                                   const float* __restrict__ v,
                                                   const float* __restrict__ mask) {
  int blk = blockIdx.x;
  int qt = blk % NQT;
  int bh = blk / NQT;
  int h = bh % Hn;
  int b = bh / Hn;
  __shared__ float Qs[TQ][Dn + 1];
  __shared__ float Ks[TK][Dn + 1];
  __shared__ float Vs[TK][Dn + 1];
  __shared__ float Ps[TQ][TK + 1];
  int tid = threadIdx.x;
  int qi = tid >> 4, kb2 = tid & 15;
  for (int i = tid; i < TQ * Dn; i += 256) {
    int qq = i / Dn, dd = i % Dn;
    int qg2 = qt * TQ + qq;
    Qs[qq][dd] = (qg2 < Nn) ? q[((size_t)(b * Nn + qg2)) * Cn + h * Dn + dd] : 0.f;
  }
  float acc[5] = {0.f, 0.f, 0.f, 0.f, 0.f};
  float m_i = -INFINITY, l_i = 0.f;
  __syncthreads();
  int qg = qt * TQ + qi;
  for (int kt = 0; kt < Nn; kt += TK) {
    for (int i = tid; i < TK * Dn; i += 256) {
      int kk = i / Dn, dd = i % Dn;
      int kg = kt + kk;
      float kv = 0.f, vv = 0.f;
      if (kg < Nn) {
        size_t base = ((size_t)(b * Nn + kg)) * Cn + h * Dn + dd;
        kv = k[base];
        vv = v[base];
      }
      Ks[kk][dd] = kv;
      Vs[kk][dd] = vv;
    }
    __syncthreads();
    float sreg[4];
#pragma unroll
    for (int j = 0; j < 4; ++j) {
      int kk = kb2 + 16 * j;
      int kg = kt + kk;
      float s = 0.f;
#pragma unroll 8
      for (int dd = 0; dd < Dn; ++dd) s += Qs[qi][dd] * Ks[kk][dd];
      s *= SCALEf;
      if (kg < Nn && qg < Nn) {
        s += mask[((size_t)(b * Nn + qg)) * Nn + kg];
      } else {
        s = -INFINITY;
      }
      sreg[j] = s;
    }
    float mloc = fmaxf(fmaxf(sreg[0], sreg[1]), fmaxf(sreg[2], sreg[3]));
#pragma unroll
    for (int o2 = 1; o2 < 16; o2 <<= 1) mloc = fmaxf(mloc, __shfl_xor(mloc, o2));
    float m_new = fmaxf(m_i, mloc);
    if (m_new == -INFINITY) m_new = 0.f;  // fully-masked padding rows
    float psum = 0.f;
#pragma unroll
    for (int j = 0; j < 4; ++j) {
      float p = expf(sreg[j] - m_new);
      Ps[qi][kb2 + 16 * j] = p;
      psum += p;
    }
#pragma unroll
    for (int o2 = 1; o2 < 16; o2 <<= 1) psum += __shfl_xor(psum, o2);
    float alpha = (m_i == -INFINITY) ? 0.f : expf(m_i - m_new);
    l_i = l_i * alpha + psum;
    m_i = m_new;
#pragma unroll
    for (int j = 0; j < 5; ++j) acc[j] *= alpha;
    for (int kk = 0; kk < TK; ++kk) {
      float p = Ps[qi][kk];
#pragma unroll
      for (int j = 0; j < 5; ++j) {
        int dd = kb2 + 16 * j;
        if (dd < Dn) acc[j] += p * Vs[kk][dd];
      }
    }
    __syncthreads();
  }
  if (qg < Nn) {
    float linv = (l_i > 0.f) ? 1.f / l_i : 0.f;
#pragma unroll
    for (int j = 0; j < 5; ++j) {
      int dd = kb2 + 16 * j;
      if (dd < Dn) q[((size_t)(b * Nn + qg)) * Cn + h * Dn + dd] = acc[j] * linv;
    }
  }
}

// -------- ToMe merge (fp32): [B,729,C] -> [B,706,C] --------
__global__ __launch_bounds__(256) void tome_merge_kernel(const float* __restrict__ h,
                                                         const int* __restrict__ unm,
                                                         const int* __restrict__ srcI,
                                                         const int* __restrict__ dstI,
                                                         const float* __restrict__ cnt,
                                                         float* __restrict__ mg) {
  int blk = blockIdx.x;
  int t = blk % NMn;
  int b = blk / NMn;
  __shared__ int s_src[Rn], s_dst[Rn];
  if (threadIdx.x < Rn) {
    s_src[threadIdx.x] = clampi(srcI[b * Rn + threadIdx.x], 0, NAn - 1);
    s_dst[threadIdx.x] = clampi(dstI[b * Rn + threadIdx.x], 0, NBn - 1);
  }
  __syncthreads();
  if (t < UNMn) {
    int tok = clampi(2 * clampi(unm[(size_t)b * UNMn + t], 0, NAn - 1), 0, Nn - 1);
    for (int c = threadIdx.x; c < Cn; c += 256)
      mg[((size_t)(b * NMn + t)) * Cn + c] = h[((size_t)(b * Nn + tok)) * Cn + c];
  } else {
    int j = t - UNMn;
    int tok = 2 * j + 1;
    float inv = 1.f / cnt[b * NBn + j];
    for (int c = threadIdx.x; c < Cn; c += 256) {
      float vsum = h[((size_t)(b * Nn + tok)) * Cn + c];
      for (int r2 = 0; r2 < Rn; ++r2)
        if (s_dst[r2] == j) vsum += h[((size_t)(b * Nn + 2 * s_src[r2])) * Cn + c];
      mg[((size_t)(b * NMn + t)) * Cn + c] = vsum * inv;
    }
  }
}

inline int cdiv(int a, int b) { return (a + b - 1) / b; }

}  // namespace

extern "C" void kernel_launch(void* const* d_in, const int* in_sizes, int n_in,
                              void* d_out, int out_size, void* d_ws, size_t ws_size,
                              hipStream_t stream) {
  // Inputs/output raw fp32 (established: fp32 reads never NaN'd; bf16 reads did).
  const float* hidden = (const float*)d_in[0];
  const float* mask   = (const float*)d_in[1];
  const float* wq = (const float*)d_in[2];
  const float* bq = (const float*)d_in[3];
  const float* wk = (const float*)d_in[4];
  const float* bk = (const float*)d_in[5];
  const float* wv = (const float*)d_in[6];
  const float* bv = (const float*)d_in[7];
  const float* wo = (const float*)d_in[8];
  const float* bo = (const float*)d_in[9];
  const float* ln1w = (const float*)d_in[10];
  const float* ln1b = (const float*)d_in[11];
  const float* ln2w = (const float*)d_in[12];
  const float* ln2b = (const float*)d_in[13];
  const float* fc1w = (const float*)d_in[14];
  const float* fc1b = (const float*)d_in[15];
  const float* fc2w = (const float*)d_in[16];
  const float* fc2b = (const float*)d_in[17];
  float* out = (float*)d_out;
  (void)in_sizes; (void)n_in; (void)out_size; (void)ws_size;

  char* ws = (char*)d_ws;
  size_t off = 0;
  auto alloc = [&](size_t nbytes) -> void* {
    void* p = ws + off;
    off += (nbytes + 255) & ~(size_t)255;
    return p;
  };
  int rows = Bn * Nn;    // 5832
  int mrows = Bn * NMn;  // 5648
  size_t bnc = (size_t)rows * Cn;
  // ws total ~85 MB (R0-sub proved ~139 MB runs).
  float* qb = (float*)alloc(bnc * 4);             // q -> attn-out (in-place) -> ffn chunk
  float* kb = (float*)alloc(bnc * 4);             // k -> hbuf
  float* vb = (float*)alloc(bnc * 4);             // v -> mg
  double* mnD = (double*)alloc((size_t)rows * Dn * 8);
  double* wkavgD = (double*)alloc((size_t)Cn * Dn * 8);
  double* bkavgD = (double*)alloc((size_t)Dn * 8);
  float* stats1f = (float*)alloc((size_t)rows * 2 * 4);
  double* stats1d = (double*)alloc((size_t)rows * 2 * 8);
  float* stats2f = (float*)alloc((size_t)mrows * 2 * 4);
  double* nmaxD = (double*)alloc((size_t)Bn * NAn * 8);
  int* nidx = (int*)alloc((size_t)Bn * NAn * 4);
  int* unm  = (int*)alloc((size_t)Bn * UNMn * 4);
  int* srcI = (int*)alloc((size_t)Bn * Rn * 4);
  int* dstI = (int*)alloc((size_t)Bn * Rn * 4);
  float* cnt = (float*)alloc((size_t)Bn * NBn * 4);
  // Overlays (stream-ordered lifetimes, R4-sub-proven pattern):
  float* hbuf = kb;                               // after attn consumed k
  float* mg = vb;                                 // after attn consumed v
  float* ffn = qb;                                // after wo-gemm consumed attn-out
  constexpr int CHUNK = 1412;                     // CHUNK*Fn*4 = 24.3 MB <= qb slot (26.9 MB)

  // 1. LN1 stats (fp32 for value GEMMs + fp64 for decision path)
  ln_stats_kernel<<<rows, 256, 0, stream>>>(hidden, stats1f, stats1d, rows);

  // 2. Decision path, all fp64: metric -> scores -> argmax -> stable sort
  wkavg_kernel<<<Cn, 128, 0, stream>>>(wk, bk, wkavgD, bkavgD);
  metric_d_kernel<<<rows, 128, 0, stream>>>(hidden, stats1d, ln1w, ln1b, wkavgD, bkavgD, mnD);
  tome_score_kernel<<<Bn * NAn, 128, 0, stream>>>(mnD, nmaxD, nidx);
  tome_sort_kernel<<<Bn, 512, 0, stream>>>(nmaxD, nidx, unm, srcI, dstI, cnt);

  // 3. QKV projections with fused LN1 (fp32 value path)
  dim3 g1(cdiv(Cn, BN), cdiv(rows, BM));
  gemm_kernel<<<g1, 256, 0, stream>>>(hidden, stats1f, ln1w, ln1b, wq, bq, nullptr, qb, rows, Cn, Cn, 0);
  gemm_kernel<<<g1, 256, 0, stream>>>(hidden, stats1f, ln1w, ln1b, wk, bk, nullptr, kb, rows, Cn, Cn, 0);
  gemm_kernel<<<g1, 256, 0, stream>>>(hidden, stats1f, ln1w, ln1b, wv, bv, nullptr, vb, rows, Cn, Cn, 0);

  // 4. Attention (output in-place over q)
  attn_kernel<<<Bn * Hn * NQT, 256, 0, stream>>>(qb, kb, vb, mask);

  // 5. Out-proj + residual(hidden) -> hbuf (overlays k)
  gemm_kernel<<<g1, 256, 0, stream>>>(qb, nullptr, nullptr, nullptr, wo, bo, hidden, hbuf, rows, Cn, Cn, 0);

  // 6. ToMe merge -> mg (overlays v)
  tome_merge_kernel<<<Bn * NMn, 256, 0, stream>>>(hbuf, unm, srcI, dstI, cnt, mg);

  // 7. LN2 stats (fused into fc1)
  ln_stats_kernel<<<mrows, 256, 0, stream>>>(mg, stats2f, (double*)nullptr, mrows);

  // 8. MLP, chunked so ffn fits the q slot; fc2 adds resid(mg) and writes d_out
  for (int c0 = 0; c0 < mrows; c0 += CHUNK) {
    int m = (mrows - c0 < CHUNK) ? (mrows - c0) : CHUNK;
    dim3 gf1(cdiv(Fn, BN), cdiv(m, BM));
    gemm_kernel<<<gf1, 256, 0, stream>>>(mg + (size_t)c0 * Cn, stats2f + 2 * c0, ln2w, ln2b,
                                         fc1w, fc1b, nullptr, ffn, m, Fn, Cn, 1);
    dim3 gf2(cdiv(Cn, BN), cdiv(m, BM));
    gemm_kernel<<<gf2, 256, 0, stream>>>(ffn, nullptr, nullptr, nullptr, fc2w, fc2b,
                                         mg + (size_t)c0 * Cn, out + (size_t)c0 * Cn, m, Cn, Fn, 0);
  }
}

// Round 7
// 3403.764 us; speedup vs baseline: 2.4808x; 2.4808x over previous
//
#include <hip/hip_runtime.h>
#include <hip/hip_bf16.h>
#include <math.h>

namespace {

constexpr int Bn = 8;
constexpr int Nn = 729;
constexpr int Cn = 1152;
constexpr int Hn = 16;
constexpr int Dn = 72;
constexpr int Fn = 4304;
constexpr int Rn = 23;
constexpr int NAn = 365;              // even tokens (src half)
constexpr int NBn = 364;              // odd tokens (dst half)
constexpr int NMn = 706;              // N - R merged tokens
constexpr int UNMn = NAn - Rn;        // 342 unmerged
constexpr float EPSf = 1e-6f;
constexpr float SCALEf = 0.11785113019775793f;  // 72^-0.5

using bf16 = __hip_bfloat16;
typedef short v8s __attribute__((ext_vector_type(8)));
typedef float v4f __attribute__((ext_vector_type(4)));

__device__ __forceinline__ float toF(bf16 v) { return __bfloat162float(v); }
__device__ __forceinline__ void stF(float* p, float v) { *p = v; }
__device__ __forceinline__ void stF(bf16* p, float v) { *p = __float2bfloat16(v); }

__device__ __forceinline__ float geluf(float x) {
  float x3 = x * x * x;
  return 0.5f * x * (1.f + tanhf(0.7978845608028654f * (x + 0.044715f * x3)));
}

__device__ __forceinline__ int clampi(int v, int lo, int hi) {
  return v < lo ? lo : (v > hi ? hi : v);
}

// -------- LN stats: one block per row; fp32 (value path) + optional fp64 (decision path) --------
__global__ __launch_bounds__(256) void ln_stats_kernel(const float* __restrict__ x,
                                                       float* __restrict__ sf,
                                                       double* __restrict__ sd,
                                                       int rows) {
  int row = blockIdx.x;
  if (row >= rows) return;
  const float* xr = x + (size_t)row * Cn;
  double s = 0.0, s2 = 0.0;
  for (int c = threadIdx.x; c < Cn; c += 256) {
    double v = (double)xr[c];
    s += v; s2 += v * v;
  }
  __shared__ double sh[8];
#pragma unroll
  for (int o = 32; o > 0; o >>= 1) { s += __shfl_down(s, o); s2 += __shfl_down(s2, o); }
  int w = threadIdx.x >> 6;
  if ((threadIdx.x & 63) == 0) { sh[w] = s; sh[4 + w] = s2; }
  __syncthreads();
  if (threadIdx.x == 0) {
    double ts = sh[0] + sh[1] + sh[2] + sh[3];
    double ts2 = sh[4] + sh[5] + sh[6] + sh[7];
    double mean = ts / Cn;
    double var = ts2 / Cn - mean * mean;
    double rstd = 1.0 / sqrt(var + (double)EPSf);
    sf[2 * row] = (float)mean;
    sf[2 * row + 1] = (float)rstd;
    if (sd) { sd[2 * row] = mean; sd[2 * row + 1] = rstd; }
  }
}

// -------- LN apply -> bf16 tensor --------
__global__ __launch_bounds__(256) void ln_apply_kernel(const float* __restrict__ x,
                                                       const float* __restrict__ stats,
                                                       const float* __restrict__ g,
                                                       const float* __restrict__ b,
                                                       bf16* __restrict__ y) {
  int row = blockIdx.x;
  float mean = stats[2 * row], rstd = stats[2 * row + 1];
  const float* xr = x + (size_t)row * Cn;
  bf16* yr = y + (size_t)row * Cn;
  for (int c = threadIdx.x; c < Cn; c += 256)
    yr[c] = __float2bfloat16((xr[c] - mean) * rstd * g[c] + b[c]);
}

// -------- Weight transpose+convert: W[K][N] fp32 -> Wt[N][K] bf16 --------
__global__ __launch_bounds__(256) void wconv_kernel(const float* __restrict__ W,
                                                    bf16* __restrict__ Wt,
                                                    int K, int N) {
  __shared__ float tile[32][33];
  int kt = blockIdx.y * 32, nt = blockIdx.x * 32;
  int tx = threadIdx.x & 31, ty = threadIdx.x >> 5;  // ty 0..7
#pragma unroll
  for (int yy = 0; yy < 4; ++yy) {
    int k = kt + ty * 4 + yy, n = nt + tx;
    tile[ty * 4 + yy][tx] = (k < K && n < N) ? W[(size_t)k * N + n] : 0.f;
  }
  __syncthreads();
#pragma unroll
  for (int yy = 0; yy < 4; ++yy) {
    int n = nt + ty * 4 + yy, k = kt + tx;
    if (n < N && k < K) Wt[(size_t)n * K + k] = __float2bfloat16(tile[tx][ty * 4 + yy]);
  }
}

// -------- MFMA GEMM: C = A[M,K](bf16) @ Wt[N,K]^T(bf16) + bias(f32) (+gelu)(+resid f32) -> OT ----
// 128x128 tile, BK=32, 4 waves in 2x2, each wave 4x4 of 16x16x32 MFMA. fp32 accum.
// LDS rows padded to 40 elems (80B): 16B-aligned ds_read_b128, only free 2-way bank conflicts.
template <typename OT>
__global__ __launch_bounds__(256) void mfma_gemm(const bf16* __restrict__ A,
                                                 const bf16* __restrict__ Wt,
                                                 const float* __restrict__ bias,
                                                 const float* __restrict__ resid,
                                                 OT* __restrict__ Cout,
                                                 int M, int N, int K, int act) {
  __align__(16) __shared__ short As[128 * 40];
  __align__(16) __shared__ short Bs[128 * 40];
  int bm = blockIdx.y * 128, bn = blockIdx.x * 128;
  int tid = threadIdx.x;
  int lane = tid & 63, w = tid >> 6;
  int wm = w >> 1, wn = w & 1;
  int l16 = lane & 15, quad = lane >> 4;
  int srow = tid >> 2, skc = (tid & 3) * 8;
  v4f acc[4][4];
#pragma unroll
  for (int i = 0; i < 4; ++i)
#pragma unroll
    for (int j = 0; j < 4; ++j) acc[i][j] = (v4f){0.f, 0.f, 0.f, 0.f};
  int ksteps = (K + 31) / 32;
  for (int ks = 0; ks < ksteps; ++ks) {
    int k0 = ks * 32;
    __syncthreads();
#pragma unroll
    for (int h = 0; h < 2; ++h) {
      int r = srow + h * 64;
      int4 za = {0, 0, 0, 0}, zb = {0, 0, 0, 0};
      if (k0 + skc < K) {  // K%8==0 so group-granular guard is exact
        if (bm + r < M) za = *reinterpret_cast<const int4*>(A + (size_t)(bm + r) * K + k0 + skc);
        if (bn + r < N) zb = *reinterpret_cast<const int4*>(Wt + (size_t)(bn + r) * K + k0 + skc);
      }
      *reinterpret_cast<int4*>(&As[r * 40 + skc]) = za;
      *reinterpret_cast<int4*>(&Bs[r * 40 + skc]) = zb;
    }
    __syncthreads();
    v8s af[4], bfr[4];
#pragma unroll
    for (int i = 0; i < 4; ++i)
      af[i] = *reinterpret_cast<const v8s*>(&As[(wm * 64 + i * 16 + l16) * 40 + quad * 8]);
#pragma unroll
    for (int j = 0; j < 4; ++j)
      bfr[j] = *reinterpret_cast<const v8s*>(&Bs[(wn * 64 + j * 16 + l16) * 40 + quad * 8]);
#pragma unroll
    for (int i = 0; i < 4; ++i)
#pragma unroll
      for (int j = 0; j < 4; ++j)
        acc[i][j] = __builtin_amdgcn_mfma_f32_16x16x32_bf16(af[i], bfr[j], acc[i][j], 0, 0, 0);
  }
  // Epilogue: C/D layout col=lane&15, row=quad*4+reg (m89-verified)
#pragma unroll
  for (int i = 0; i < 4; ++i) {
#pragma unroll
    for (int j = 0; j < 4; ++j) {
#pragma unroll
      for (int r = 0; r < 4; ++r) {
        int row = bm + wm * 64 + i * 16 + quad * 4 + r;
        int col = bn + wn * 64 + j * 16 + l16;
        if (row < M && col < N) {
          float v = acc[i][j][r] + bias[col];
          if (act) v = geluf(v);
          if (resid) v += resid[(size_t)row * N + col];
          stF(&Cout[(size_t)row * N + col], v);
        }
      }
    }
  }
}

// -------- Decision path (fp64, unchanged from R6 — it is what makes ToMe match np) --------
__global__ __launch_bounds__(128) void wkavg_kernel(const float* __restrict__ wk,
                                                    const float* __restrict__ bk,
                                                    double* __restrict__ wka,
                                                    double* __restrict__ bka) {
  int c = blockIdx.x;
  int d = threadIdx.x;
  if (d < Dn) {
    double s = 0.0;
    for (int h = 0; h < Hn; ++h) s += (double)wk[(size_t)c * Cn + h * Dn + d];
    wka[(size_t)c * Dn + d] = s / Hn;
    if (c == 0) {
      double t = 0.0;
      for (int h = 0; h < Hn; ++h) t += (double)bk[h * Dn + d];
      bka[d] = t / Hn;
    }
  }
}

__global__ __launch_bounds__(128) void metric_d_kernel(const float* __restrict__ x,
                                                       const double* __restrict__ sd,
                                                       const float* __restrict__ g,
                                                       const float* __restrict__ b,
                                                       const double* __restrict__ wka,
                                                       const double* __restrict__ bka,
                                                       double* __restrict__ mn) {
  int row = blockIdx.x;  // b*N + n
  __shared__ double as_[Cn];
  __shared__ double red[Dn];
  __shared__ double nrm;
  double mean = sd[2 * row], rstd = sd[2 * row + 1];
  const float* xr = x + (size_t)row * Cn;
  for (int c = threadIdx.x; c < Cn; c += 128)
    as_[c] = ((double)xr[c] - mean) * rstd * (double)g[c] + (double)b[c];
  __syncthreads();
  int d = threadIdx.x;
  double acc = 0.0;
  if (d < Dn) {
    for (int c = 0; c < Cn; ++c) acc += as_[c] * wka[(size_t)c * Dn + d];
    acc += bka[d];
    red[d] = acc * acc;
  }
  __syncthreads();
  if (threadIdx.x == 0) {
    double t = 0.0;
    for (int i = 0; i < Dn; ++i) t += red[i];
    nrm = 1.0 / sqrt(t > 0.0 ? t : 1e-300);
  }
  __syncthreads();
  if (d < Dn) mn[(size_t)row * Dn + d] = acc * nrm;
}

__global__ __launch_bounds__(128) void tome_score_kernel(const double* __restrict__ mn,
                                                         double* __restrict__ nmax,
                                                         int* __restrict__ nidx) {
  int blk = blockIdx.x;
  int i = blk % NAn;
  int b = blk / NAn;
  __shared__ double av[Dn];
  __shared__ double sv[128];
  __shared__ int si[128];
  int tid = threadIdx.x;
  if (tid < Dn) av[tid] = mn[((size_t)(b * Nn) + 2 * i) * Dn + tid];
  __syncthreads();
  double best = -1e300;
  int bi = 0;
  for (int c2 = tid; c2 < NBn; c2 += 128) {
    const double* bv = mn + ((size_t)(b * Nn) + 2 * c2 + 1) * Dn;
    double s = 0.0;
#pragma unroll 8
    for (int dd = 0; dd < Dn; ++dd) s += av[dd] * bv[dd];
    if (s > best) { best = s; bi = c2; }  // strict > keeps first occurrence
  }
  sv[tid] = best;
  si[tid] = bi;
  __syncthreads();
  if (tid == 0) {
    double bb = sv[0];
    int ii = si[0];
    for (int t2 = 1; t2 < 128; ++t2) {
      if (sv[t2] > bb || (sv[t2] == bb && si[t2] < ii)) { bb = sv[t2]; ii = si[t2]; }
    }
    nmax[b * NAn + i] = bb;
    nidx[b * NAn + i] = clampi(ii, 0, NBn - 1);
  }
}

__global__ __launch_bounds__(512) void tome_sort_kernel(const double* __restrict__ nmax,
                                                        const int* __restrict__ nidx,
                                                        int* __restrict__ unm,
                                                        int* __restrict__ srcI,
                                                        int* __restrict__ dstI,
                                                        float* __restrict__ cnt) {
  int b = blockIdx.x;
  __shared__ double v[NAn];
  __shared__ int eidx[NAn];
  __shared__ int dsts[Rn];
  int tid = threadIdx.x;
  for (int i = tid; i < NAn; i += blockDim.x) {
    v[i] = nmax[b * NAn + i];
    eidx[i] = i;  // defensive init
  }
  __syncthreads();
  for (int i = tid; i < NAn; i += blockDim.x) {
    double vi = v[i];
    int rank = 0;
    for (int j = 0; j < NAn; ++j) {
      double vj = v[j];
      rank += (vj > vi) || (vj == vi && j < i);  // stable descending
    }
    eidx[clampi(rank, 0, NAn - 1)] = i;
  }
  __syncthreads();
  for (int r2 = tid; r2 < NAn; r2 += blockDim.x) {
    if (r2 >= Rn) unm[(size_t)b * UNMn + (r2 - Rn)] = clampi(eidx[r2], 0, NAn - 1);
  }
  if (tid < Rn) {
    int s = clampi(eidx[tid], 0, NAn - 1);
    srcI[b * Rn + tid] = s;
    int dd = clampi(nidx[b * NAn + s], 0, NBn - 1);
    dsts[tid] = dd;
    dstI[b * Rn + tid] = dd;
  }
  for (int j = tid; j < NBn; j += blockDim.x) cnt[(size_t)b * NBn + j] = 1.f;
  __syncthreads();
  if (tid == 0) {
    for (int r2 = 0; r2 < Rn; ++r2) cnt[(size_t)b * NBn + dsts[r2]] += 1.f;
  }
}

// -------- Flash attention (bf16 in/out, fp32 math); writes output IN-PLACE over q --------
constexpr int TQ = 16, TK = 64;
constexpr int NQT = (Nn + TQ - 1) / TQ;  // 46
__global__ __launch_bounds__(256) void attn_kernel(bf16* q /* in: q, out: attn */,
                                                   const bf16* __restrict__ k,
                                                   const bf16* __restrict__ v,
                                                   const float* __restrict__ mask) {
  int blk = blockIdx.x;
  int qt = blk % NQT;
  int bh = blk / NQT;
  int h = bh % Hn;
  int b = bh / Hn;
  __shared__ float Qs[TQ][Dn + 1];
  __shared__ float Ks[TK][Dn + 1];
  __shared__ float Vs[TK][Dn + 1];
  __shared__ float Ps[TQ][TK + 1];
  int tid = threadIdx.x;
  int qi = tid >> 4, kb2 = tid & 15;
  for (int i = tid; i < TQ * Dn; i += 256) {
    int qq = i / Dn, dd = i % Dn;
    int qg2 = qt * TQ + qq;
    Qs[qq][dd] = (qg2 < Nn) ? toF(q[((size_t)(b * Nn + qg2)) * Cn + h * Dn + dd]) : 0.f;
  }
  float acc[5] = {0.f, 0.f, 0.f, 0.f, 0.f};
  float m_i = -INFINITY, l_i = 0.f;
  __syncthreads();
  int qg = qt * TQ + qi;
  for (int kt = 0; kt < Nn; kt += TK) {
    for (int i = tid; i < TK * Dn; i += 256) {
      int kk = i / Dn, dd = i % Dn;
      int kg = kt + kk;
      float kv = 0.f, vv = 0.f;
      if (kg < Nn) {
        size_t base = ((size_t)(b * Nn + kg)) * Cn + h * Dn + dd;
        kv = toF(k[base]);
        vv = toF(v[base]);
      }
      Ks[kk][dd] = kv;
      Vs[kk][dd] = vv;
    }
    __syncthreads();
    float sreg[4];
#pragma unroll
    for (int j = 0; j < 4; ++j) {
      int kk = kb2 + 16 * j;
      int kg = kt + kk;
      float s = 0.f;
#pragma unroll 8
      for (int dd = 0; dd < Dn; ++dd) s += Qs[qi][dd] * Ks[kk][dd];
      s *= SCALEf;
      if (kg < Nn && qg < Nn) {
        s += mask[((size_t)(b * Nn + qg)) * Nn + kg];
      } else {
        s = -INFINITY;
      }
      sreg[j] = s;
    }
    float mloc = fmaxf(fmaxf(sreg[0], sreg[1]), fmaxf(sreg[2], sreg[3]));
#pragma unroll
    for (int o2 = 1; o2 < 16; o2 <<= 1) mloc = fmaxf(mloc, __shfl_xor(mloc, o2));
    float m_new = fmaxf(m_i, mloc);
    if (m_new == -INFINITY) m_new = 0.f;  // fully-masked padding rows
    float psum = 0.f;
#pragma unroll
    for (int j = 0; j < 4; ++j) {
      float p = expf(sreg[j] - m_new);
      Ps[qi][kb2 + 16 * j] = p;
      psum += p;
    }
#pragma unroll
    for (int o2 = 1; o2 < 16; o2 <<= 1) psum += __shfl_xor(psum, o2);
    float alpha = (m_i == -INFINITY) ? 0.f : expf(m_i - m_new);
    l_i = l_i * alpha + psum;
    m_i = m_new;
#pragma unroll
    for (int j = 0; j < 5; ++j) acc[j] *= alpha;
    for (int kk = 0; kk < TK; ++kk) {
      float p = Ps[qi][kk];
#pragma unroll
      for (int j = 0; j < 5; ++j) {
        int dd = kb2 + 16 * j;
        if (dd < Dn) acc[j] += p * Vs[kk][dd];
      }
    }
    __syncthreads();
  }
  if (qg < Nn) {
    float linv = (l_i > 0.f) ? 1.f / l_i : 0.f;
#pragma unroll
    for (int j = 0; j < 5; ++j) {
      int dd = kb2 + 16 * j;
      if (dd < Dn) q[((size_t)(b * Nn + qg)) * Cn + h * Dn + dd] = __float2bfloat16(acc[j] * linv);
    }
  }
}

// -------- ToMe merge (fp32): [B,729,C] -> [B,706,C] --------
__global__ __launch_bounds__(256) void tome_merge_kernel(const float* __restrict__ h,
                                                         const int* __restrict__ unm,
                                                         const int* __restrict__ srcI,
                                                         const int* __restrict__ dstI,
                                                         const float* __restrict__ cnt,
                                                         float* __restrict__ mg) {
  int blk = blockIdx.x;
  int t = blk % NMn;
  int b = blk / NMn;
  __shared__ int s_src[Rn], s_dst[Rn];
  if (threadIdx.x < Rn) {
    s_src[threadIdx.x] = clampi(srcI[b * Rn + threadIdx.x], 0, NAn - 1);
    s_dst[threadIdx.x] = clampi(dstI[b * Rn + threadIdx.x], 0, NBn - 1);
  }
  __syncthreads();
  if (t < UNMn) {
    int tok = clampi(2 * clampi(unm[(size_t)b * UNMn + t], 0, NAn - 1), 0, Nn - 1);
    for (int c = threadIdx.x; c < Cn; c += 256)
      mg[((size_t)(b * NMn + t)) * Cn + c] = h[((size_t)(b * Nn + tok)) * Cn + c];
  } else {
    int j = t - UNMn;
    int tok = 2 * j + 1;
    float inv = 1.f / cnt[b * NBn + j];
    for (int c = threadIdx.x; c < Cn; c += 256) {
      float vsum = h[((size_t)(b * Nn + tok)) * Cn + c];
      for (int r2 = 0; r2 < Rn; ++r2)
        if (s_dst[r2] == j) vsum += h[((size_t)(b * Nn + 2 * s_src[r2])) * Cn + c];
      mg[((size_t)(b * NMn + t)) * Cn + c] = vsum * inv;
    }
  }
}

inline int cdiv(int a, int b) { return (a + b - 1) / b; }

}  // namespace

extern "C" void kernel_launch(void* const* d_in, const int* in_sizes, int n_in,
                              void* d_out, int out_size, void* d_ws, size_t ws_size,
                              hipStream_t stream) {
  const float* hidden = (const float*)d_in[0];
  const float* mask   = (const float*)d_in[1];
  const float* wq = (const float*)d_in[2];
  const float* bq = (const float*)d_in[3];
  const float* wk = (const float*)d_in[4];
  const float* bk = (const float*)d_in[5];
  const float* wv = (const float*)d_in[6];
  const float* bv = (const float*)d_in[7];
  const float* wo = (const float*)d_in[8];
  const float* bo = (const float*)d_in[9];
  const float* ln1w = (const float*)d_in[10];
  const float* ln1b = (const float*)d_in[11];
  const float* ln2w = (const float*)d_in[12];
  const float* ln2b = (const float*)d_in[13];
  const float* fc1w = (const float*)d_in[14];
  const float* fc1b = (const float*)d_in[15];
  const float* fc2w = (const float*)d_in[16];
  const float* fc2b = (const float*)d_in[17];
  float* out = (float*)d_out;
  (void)in_sizes; (void)n_in; (void)out_size; (void)ws_size;

  char* ws = (char*)d_ws;
  size_t off = 0;
  auto alloc = [&](size_t nbytes) -> void* {
    void* p = ws + off;
    off += (nbytes + 255) & ~(size_t)255;
    return p;
  };
  int rows = Bn * Nn;    // 5832
  int mrows = Bn * NMn;  // 5648
  size_t bnc = (size_t)rows * Cn;
  // ws total ~126 MB (R0-sub proved ~134 MB runs).
  bf16* wqT = (bf16*)alloc((size_t)Cn * Cn * 2);
  bf16* wkT = (bf16*)alloc((size_t)Cn * Cn * 2);
  bf16* wvT = (bf16*)alloc((size_t)Cn * Cn * 2);
  bf16* woT = (bf16*)alloc((size_t)Cn * Cn * 2);
  bf16* fc1T = (bf16*)alloc((size_t)Fn * Cn * 2);
  bf16* fc2T = (bf16*)alloc((size_t)Cn * Fn * 2);
  bf16* xlnB = (bf16*)alloc(bnc * 2);             // LN1 out; later overlaid by mg (with qb)
  bf16* qb = (bf16*)alloc(bnc * 2);               // q -> attn-out (in-place)
  bf16* kb = (bf16*)alloc(bnc * 2);               // k; later overlaid by hbuf (with vb)
  bf16* vb = (bf16*)alloc(bnc * 2);               // v
  bf16* h2B = (bf16*)alloc((size_t)mrows * Cn * 2);
  constexpr int CHUNK = 2824;                     // mrows/2
  bf16* ffnB = (bf16*)alloc((size_t)CHUNK * Fn * 2);
  double* mnD = (double*)alloc((size_t)rows * Dn * 8);
  double* wkavgD = (double*)alloc((size_t)Cn * Dn * 8);
  double* bkavgD = (double*)alloc((size_t)Dn * 8);
  float* stats1f = (float*)alloc((size_t)rows * 2 * 4);
  double* stats1d = (double*)alloc((size_t)rows * 2 * 8);
  float* stats2f = (float*)alloc((size_t)mrows * 2 * 4);
  double* nmaxD = (double*)alloc((size_t)Bn * NAn * 8);
  int* nidx = (int*)alloc((size_t)Bn * NAn * 4);
  int* unm  = (int*)alloc((size_t)Bn * UNMn * 4);
  int* srcI = (int*)alloc((size_t)Bn * Rn * 4);
  int* dstI = (int*)alloc((size_t)Bn * Rn * 4);
  float* cnt = (float*)alloc((size_t)Bn * NBn * 4);
  // Overlays (stream-ordered lifetimes; each bf16 slot is 13,436,928 B, 256-aligned, contiguous):
  float* hbuf = (float*)kb;   // 26.87 MB over kb+vb (dead after attn)
  float* mg   = (float*)xlnB; // 26.03 MB over xlnB+qb (dead after QKV / wo-gemm)

  // 0. Weight transpose+convert to bf16 [N][K]
  wconv_kernel<<<dim3(cdiv(Cn, 32), cdiv(Cn, 32)), 256, 0, stream>>>(wq, wqT, Cn, Cn);
  wconv_kernel<<<dim3(cdiv(Cn, 32), cdiv(Cn, 32)), 256, 0, stream>>>(wk, wkT, Cn, Cn);
  wconv_kernel<<<dim3(cdiv(Cn, 32), cdiv(Cn, 32)), 256, 0, stream>>>(wv, wvT, Cn, Cn);
  wconv_kernel<<<dim3(cdiv(Cn, 32), cdiv(Cn, 32)), 256, 0, stream>>>(wo, woT, Cn, Cn);
  wconv_kernel<<<dim3(cdiv(Fn, 32), cdiv(Cn, 32)), 256, 0, stream>>>(fc1w, fc1T, Cn, Fn);
  wconv_kernel<<<dim3(cdiv(Cn, 32), cdiv(Fn, 32)), 256, 0, stream>>>(fc2w, fc2T, Fn, Cn);

  // 1. LN1 stats (fp32 + fp64)
  ln_stats_kernel<<<rows, 256, 0, stream>>>(hidden, stats1f, stats1d, rows);

  // 2. Decision path, all fp64 (exactly matches np reference decisions)
  wkavg_kernel<<<Cn, 128, 0, stream>>>(wk, bk, wkavgD, bkavgD);
  metric_d_kernel<<<rows, 128, 0, stream>>>(hidden, stats1d, ln1w, ln1b, wkavgD, bkavgD, mnD);
  tome_score_kernel<<<Bn * NAn, 128, 0, stream>>>(mnD, nmaxD, nidx);
  tome_sort_kernel<<<Bn, 512, 0, stream>>>(nmaxD, nidx, unm, srcI, dstI, cnt);

  // 3. LN1 apply -> bf16
  ln_apply_kernel<<<rows, 256, 0, stream>>>(hidden, stats1f, ln1w, ln1b, xlnB);

  // 4. QKV projections (bf16 MFMA)
  dim3 g1(cdiv(Cn, 128), cdiv(rows, 128));
  mfma_gemm<bf16><<<g1, 256, 0, stream>>>(xlnB, wqT, bq, nullptr, qb, rows, Cn, Cn, 0);
  mfma_gemm<bf16><<<g1, 256, 0, stream>>>(xlnB, wkT, bk, nullptr, kb, rows, Cn, Cn, 0);
  mfma_gemm<bf16><<<g1, 256, 0, stream>>>(xlnB, wvT, bv, nullptr, vb, rows, Cn, Cn, 0);

  // 5. Attention (in-place over q)
  attn_kernel<<<Bn * Hn * NQT, 256, 0, stream>>>(qb, kb, vb, mask);

  // 6. Out-proj + residual(hidden) -> hbuf fp32 (overlays kb+vb)
  mfma_gemm<float><<<g1, 256, 0, stream>>>(qb, woT, bo, hidden, hbuf, rows, Cn, Cn, 0);

  // 7. ToMe merge -> mg fp32 (overlays xlnB+qb)
  tome_merge_kernel<<<Bn * NMn, 256, 0, stream>>>(hbuf, unm, srcI, dstI, cnt, mg);

  // 8. LN2 stats + apply -> h2B bf16
  ln_stats_kernel<<<mrows, 256, 0, stream>>>(mg, stats2f, (double*)nullptr, mrows);
  ln_apply_kernel<<<mrows, 256, 0, stream>>>(mg, stats2f, ln2w, ln2b, h2B);

  // 9. MLP (bf16 MFMA), 2 chunks so ffnB fits; fc2 adds resid(mg) and writes fp32 d_out
  for (int c0 = 0; c0 < mrows; c0 += CHUNK) {
    int m = (mrows - c0 < CHUNK) ? (mrows - c0) : CHUNK;
    dim3 gf1(cdiv(Fn, 128), cdiv(m, 128));
    mfma_gemm<bf16><<<gf1, 256, 0, stream>>>(h2B + (size_t)c0 * Cn, fc1T, fc1b, nullptr,
                                             ffnB, m, Fn, Cn, 1);
    dim3 gf2(cdiv(Cn, 128), cdiv(m, 128));
    mfma_gemm<float><<<gf2, 256, 0, stream>>>(ffnB, fc2T, fc2b, mg + (size_t)c0 * Cn,
                                              out + (size_t)c0 * Cn, m, Cn, Fn, 0);
  }
}

// Round 8
// 1878.034 us; speedup vs baseline: 4.4961x; 1.8124x over previous
//
#include <hip/hip_runtime.h>
#include <hip/hip_bf16.h>
#include <math.h>

namespace {

constexpr int Bn = 8;
constexpr int Nn = 729;
constexpr int Cn = 1152;
constexpr int Hn = 16;
constexpr int Dn = 72;
constexpr int Fn = 4304;
constexpr int Rn = 23;
constexpr int NAn = 365;              // even tokens (src half)
constexpr int NBn = 364;              // odd tokens (dst half)
constexpr int NMn = 706;              // N - R merged tokens
constexpr int UNMn = NAn - Rn;        // 342 unmerged
constexpr float EPSf = 1e-6f;
constexpr float SCALEf = 0.11785113019775793f;  // 72^-0.5

using bf16 = __hip_bfloat16;
typedef short v8s __attribute__((ext_vector_type(8)));
typedef float v4f __attribute__((ext_vector_type(4)));

__device__ __forceinline__ float toF(bf16 v) { return __bfloat162float(v); }
__device__ __forceinline__ void stF(float* p, float v) { *p = v; }
__device__ __forceinline__ void stF(bf16* p, float v) { *p = __float2bfloat16(v); }

__device__ __forceinline__ float geluf(float x) {
  float x3 = x * x * x;
  return 0.5f * x * (1.f + tanhf(0.7978845608028654f * (x + 0.044715f * x3)));
}

__device__ __forceinline__ int clampi(int v, int lo, int hi) {
  return v < lo ? lo : (v > hi ? hi : v);
}

// -------- LN stats: one block per row; fp32 (value path) + optional fp64 (decision path) --------
__global__ __launch_bounds__(256) void ln_stats_kernel(const float* __restrict__ x,
                                                       float* __restrict__ sf,
                                                       double* __restrict__ sd,
                                                       int rows) {
  int row = blockIdx.x;
  if (row >= rows) return;
  const float* xr = x + (size_t)row * Cn;
  double s = 0.0, s2 = 0.0;
  for (int c = threadIdx.x; c < Cn; c += 256) {
    double v = (double)xr[c];
    s += v; s2 += v * v;
  }
  __shared__ double sh[8];
#pragma unroll
  for (int o = 32; o > 0; o >>= 1) { s += __shfl_down(s, o); s2 += __shfl_down(s2, o); }
  int w = threadIdx.x >> 6;
  if ((threadIdx.x & 63) == 0) { sh[w] = s; sh[4 + w] = s2; }
  __syncthreads();
  if (threadIdx.x == 0) {
    double ts = sh[0] + sh[1] + sh[2] + sh[3];
    double ts2 = sh[4] + sh[5] + sh[6] + sh[7];
    double mean = ts / Cn;
    double var = ts2 / Cn - mean * mean;
    double rstd = 1.0 / sqrt(var + (double)EPSf);
    sf[2 * row] = (float)mean;
    sf[2 * row + 1] = (float)rstd;
    if (sd) { sd[2 * row] = mean; sd[2 * row + 1] = rstd; }
  }
}

// -------- LN apply -> bf16 tensor --------
__global__ __launch_bounds__(256) void ln_apply_kernel(const float* __restrict__ x,
                                                       const float* __restrict__ stats,
                                                       const float* __restrict__ g,
                                                       const float* __restrict__ b,
                                                       bf16* __restrict__ y) {
  int row = blockIdx.x;
  float mean = stats[2 * row], rstd = stats[2 * row + 1];
  const float* xr = x + (size_t)row * Cn;
  bf16* yr = y + (size_t)row * Cn;
  for (int c = threadIdx.x; c < Cn; c += 256)
    yr[c] = __float2bfloat16((xr[c] - mean) * rstd * g[c] + b[c]);
}

// -------- Weight transpose+convert: W[K][N] fp32 -> Wt[N][K] bf16 --------
__global__ __launch_bounds__(256) void wconv_kernel(const float* __restrict__ W,
                                                    bf16* __restrict__ Wt,
                                                    int K, int N) {
  __shared__ float tile[32][33];
  int kt = blockIdx.y * 32, nt = blockIdx.x * 32;
  int tx = threadIdx.x & 31, ty = threadIdx.x >> 5;  // ty 0..7
#pragma unroll
  for (int yy = 0; yy < 4; ++yy) {
    int k = kt + ty * 4 + yy, n = nt + tx;
    tile[ty * 4 + yy][tx] = (k < K && n < N) ? W[(size_t)k * N + n] : 0.f;
  }
  __syncthreads();
#pragma unroll
  for (int yy = 0; yy < 4; ++yy) {
    int n = nt + ty * 4 + yy, k = kt + tx;
    if (n < N && k < K) Wt[(size_t)n * K + k] = __float2bfloat16(tile[tx][ty * 4 + yy]);
  }
}

// -------- MFMA GEMM: C = A[M,K](bf16) @ Wt[N,K]^T(bf16) + bias(f32) (+gelu)(+resid f32) -> OT ----
template <typename OT>
__global__ __launch_bounds__(256) void mfma_gemm(const bf16* __restrict__ A,
                                                 const bf16* __restrict__ Wt,
                                                 const float* __restrict__ bias,
                                                 const float* __restrict__ resid,
                                                 OT* __restrict__ Cout,
                                                 int M, int N, int K, int act) {
  __align__(16) __shared__ short As[128 * 40];
  __align__(16) __shared__ short Bs[128 * 40];
  int bm = blockIdx.y * 128, bn = blockIdx.x * 128;
  int tid = threadIdx.x;
  int lane = tid & 63, w = tid >> 6;
  int wm = w >> 1, wn = w & 1;
  int l16 = lane & 15, quad = lane >> 4;
  int srow = tid >> 2, skc = (tid & 3) * 8;
  v4f acc[4][4];
#pragma unroll
  for (int i = 0; i < 4; ++i)
#pragma unroll
    for (int j = 0; j < 4; ++j) acc[i][j] = (v4f){0.f, 0.f, 0.f, 0.f};
  int ksteps = (K + 31) / 32;
  for (int ks = 0; ks < ksteps; ++ks) {
    int k0 = ks * 32;
    __syncthreads();
#pragma unroll
    for (int h = 0; h < 2; ++h) {
      int r = srow + h * 64;
      int4 za = {0, 0, 0, 0}, zb = {0, 0, 0, 0};
      if (k0 + skc < K) {  // K%8==0 so group-granular guard is exact
        if (bm + r < M) za = *reinterpret_cast<const int4*>(A + (size_t)(bm + r) * K + k0 + skc);
        if (bn + r < N) zb = *reinterpret_cast<const int4*>(Wt + (size_t)(bn + r) * K + k0 + skc);
      }
      *reinterpret_cast<int4*>(&As[r * 40 + skc]) = za;
      *reinterpret_cast<int4*>(&Bs[r * 40 + skc]) = zb;
    }
    __syncthreads();
    v8s af[4], bfr[4];
#pragma unroll
    for (int i = 0; i < 4; ++i)
      af[i] = *reinterpret_cast<const v8s*>(&As[(wm * 64 + i * 16 + l16) * 40 + quad * 8]);
#pragma unroll
    for (int j = 0; j < 4; ++j)
      bfr[j] = *reinterpret_cast<const v8s*>(&Bs[(wn * 64 + j * 16 + l16) * 40 + quad * 8]);
#pragma unroll
    for (int i = 0; i < 4; ++i)
#pragma unroll
      for (int j = 0; j < 4; ++j)
        acc[i][j] = __builtin_amdgcn_mfma_f32_16x16x32_bf16(af[i], bfr[j], acc[i][j], 0, 0, 0);
  }
#pragma unroll
  for (int i = 0; i < 4; ++i) {
#pragma unroll
    for (int j = 0; j < 4; ++j) {
#pragma unroll
      for (int r = 0; r < 4; ++r) {
        int row = bm + wm * 64 + i * 16 + quad * 4 + r;
        int col = bn + wn * 64 + j * 16 + l16;
        if (row < M && col < N) {
          float v = acc[i][j][r] + bias[col];
          if (act) v = geluf(v);
          if (resid) v += resid[(size_t)row * N + col];
          stF(&Cout[(size_t)row * N + col], v);
        }
      }
    }
  }
}

// -------- MFMA flash attention: one block = (b, h, 64-query tile); in-place over q --------
// Qs/Ks: [64][104] bf16, D padded 72->96 (3 K=32 MFMA steps), stride 104 => 2-way-only conflicts.
// Vt: V^T [80][72] (d padded to 80 for 5 output col-tiles; key dim 64 used of 72 stride).
// Ps: per-wave [16][72] bf16 — C-layout -> A-layout round trip for PV.
constexpr int ATQ = 64, ATK = 64;
constexpr int NQT2 = (Nn + ATQ - 1) / ATQ;  // 12
constexpr int QSS = 104, VTS = 72, PSS = 72;
__global__ __launch_bounds__(256) void attn_mfma_kernel(bf16* q /* in: q, out: attn */,
                                                        const bf16* __restrict__ k,
                                                        const bf16* __restrict__ v,
                                                        const float* __restrict__ mask) {
  int blk = blockIdx.x;
  int qt = blk % NQT2;
  int bh = blk / NQT2;
  int h = bh % Hn;
  int b = bh / Hn;
  __align__(16) __shared__ short Qs[ATQ * QSS];
  __align__(16) __shared__ short Ks[ATK * QSS];
  __align__(16) __shared__ short Vt[80 * VTS];
  __align__(16) __shared__ short Ps[4][16 * PSS];
  int tid = threadIdx.x;
  int lane = tid & 63, w = tid >> 6;
  int l16 = lane & 15, quad = lane >> 4;

  // Stage Q once: 64 rows x 12 chunks (9 real 8-short groups + 3 zero-pad)
#pragma unroll
  for (int i = 0; i < 3; ++i) {
    int idx = tid + i * 256;
    int r = idx / 12, ch = idx % 12;
    int qg = qt * ATQ + r;
    int4 z = {0, 0, 0, 0};
    if (ch < 9 && qg < Nn)
      z = *reinterpret_cast<const int4*>(q + ((size_t)(b * Nn + qg)) * Cn + h * Dn + ch * 8);
    *reinterpret_cast<int4*>(&Qs[r * QSS + ch * 8]) = z;
  }

  v4f o[5];
#pragma unroll
  for (int dj = 0; dj < 5; ++dj) o[dj] = (v4f){0.f, 0.f, 0.f, 0.f};
  float m_r[4] = {-INFINITY, -INFINITY, -INFINITY, -INFINITY};
  float l_r[4] = {0.f, 0.f, 0.f, 0.f};

  for (int t = 0; t < NQT2; ++t) {
    int kt2 = t * ATK;
    __syncthreads();  // previous iteration's reads done before restage
    // Stage K tile (vector int4, coalesced)
#pragma unroll
    for (int i = 0; i < 3; ++i) {
      int idx = tid + i * 256;
      int r = idx / 12, ch = idx % 12;
      int kg = kt2 + r;
      int4 z = {0, 0, 0, 0};
      if (ch < 9 && kg < Nn)
        z = *reinterpret_cast<const int4*>(k + ((size_t)(b * Nn + kg)) * Cn + h * Dn + ch * 8);
      *reinterpret_cast<int4*>(&Ks[r * QSS + ch * 8]) = z;
    }
    // Stage V transposed: Vt[d][key]; scalar writes (8-way conflicts, paid once per tile)
#pragma unroll
    for (int i = 0; i < 20; ++i) {
      int idx = tid + i * 256;
      if (idx < 4608) {
        int key = idx / 72, d = idx % 72;
        int kg = kt2 + key;
        bf16 val = (kg < Nn) ? v[((size_t)(b * Nn + kg)) * Cn + h * Dn + d] : bf16(0.f);
        Vt[d * VTS + key] = *reinterpret_cast<short*>(&val);
      } else {
        int p2 = idx - 4608;  // zero pad rows d=72..79
        int d = 72 + p2 / 64, key = p2 % 64;
        Vt[d * VTS + key] = 0;
      }
    }
    __syncthreads();

    // QK^T: S[16q x 64k] per wave, 12 MFMA
    v4f sfr[4];
#pragma unroll
    for (int j = 0; j < 4; ++j) sfr[j] = (v4f){0.f, 0.f, 0.f, 0.f};
#pragma unroll
    for (int ks = 0; ks < 3; ++ks) {
      v8s aq = *reinterpret_cast<const v8s*>(&Qs[(w * 16 + l16) * QSS + ks * 32 + quad * 8]);
#pragma unroll
      for (int j = 0; j < 4; ++j) {
        v8s bk_ = *reinterpret_cast<const v8s*>(&Ks[(j * 16 + l16) * QSS + ks * 32 + quad * 8]);
        sfr[j] = __builtin_amdgcn_mfma_f32_16x16x32_bf16(aq, bk_, sfr[j], 0, 0, 0);
      }
    }
    // scale + mask (C layout: col=j*16+l16, row=quad*4+r)
    float sv[4][4];
    int qbase = qt * ATQ + w * 16 + quad * 4;
#pragma unroll
    for (int r = 0; r < 4; ++r) {
      int qg = qbase + r;
      const float* mrow = mask + ((size_t)(b * Nn + (qg < Nn ? qg : 0))) * Nn;
#pragma unroll
      for (int j = 0; j < 4; ++j) {
        int kg = kt2 + j * 16 + l16;
        float s = sfr[j][r] * SCALEf;
        sv[j][r] = (kg < Nn && qg < Nn) ? s + mrow[kg] : -INFINITY;
      }
    }
    // online softmax per row (reduce across 16 lanes of the quad-group)
    float alpha[4], psum[4];
#pragma unroll
    for (int r = 0; r < 4; ++r) {
      float mx = fmaxf(fmaxf(sv[0][r], sv[1][r]), fmaxf(sv[2][r], sv[3][r]));
#pragma unroll
      for (int o2 = 1; o2 < 16; o2 <<= 1) mx = fmaxf(mx, __shfl_xor(mx, o2));
      float mnew = fmaxf(m_r[r], mx);
      float ps = 0.f;
#pragma unroll
      for (int j = 0; j < 4; ++j) {
        float p = expf(sv[j][r] - mnew);
        Ps[w][(quad * 4 + r) * PSS + j * 16 + l16] = *reinterpret_cast<short*>(&(bf16&)(*(new(&p) bf16(__float2bfloat16(p)))));
        ps += p;
      }
#pragma unroll
      for (int o2 = 1; o2 < 16; o2 <<= 1) ps += __shfl_xor(ps, o2);
      alpha[r] = expf(m_r[r] - mnew);
      l_r[r] = l_r[r] * alpha[r] + ps;
      m_r[r] = mnew;
      psum[r] = ps;
    }
    (void)psum;
    // rescale O
#pragma unroll
    for (int dj = 0; dj < 5; ++dj)
#pragma unroll
      for (int r = 0; r < 4; ++r) o[dj][r] *= alpha[r];
    // PV: O += P[16x64] @ Vt^T, 10 MFMA (Ps write->read same wave: compiler waits lgkmcnt)
#pragma unroll
    for (int st = 0; st < 2; ++st) {
      v8s ap = *reinterpret_cast<const v8s*>(&Ps[w][l16 * PSS + st * 32 + quad * 8]);
#pragma unroll
      for (int dj = 0; dj < 5; ++dj) {
        v8s bv_ = *reinterpret_cast<const v8s*>(&Vt[(dj * 16 + l16) * VTS + st * 32 + quad * 8]);
        o[dj] = __builtin_amdgcn_mfma_f32_16x16x32_bf16(ap, bv_, o[dj], 0, 0, 0);
      }
    }
    __syncthreads();
  }
  // write out (in-place over q)
  float linv[4];
#pragma unroll
  for (int r = 0; r < 4; ++r) linv[r] = (l_r[r] > 0.f) ? 1.f / l_r[r] : 0.f;
#pragma unroll
  for (int dj = 0; dj < 5; ++dj) {
    int d = dj * 16 + l16;
    if (d >= Dn) continue;
#pragma unroll
    for (int r = 0; r < 4; ++r) {
      int qg = qt * ATQ + w * 16 + quad * 4 + r;
      if (qg < Nn)
        q[((size_t)(b * Nn + qg)) * Cn + h * Dn + d] = __float2bfloat16(o[dj][r] * linv[r]);
    }
  }
}

// -------- Decision path (fp64, unchanged — it is what makes ToMe match np) --------
__global__ __launch_bounds__(128) void wkavg_kernel(const float* __restrict__ wk,
                                                    const float* __restrict__ bk,
                                                    double* __restrict__ wka,
                                                    double* __restrict__ bka) {
  int c = blockIdx.x;
  int d = threadIdx.x;
  if (d < Dn) {
    double s = 0.0;
    for (int h = 0; h < Hn; ++h) s += (double)wk[(size_t)c * Cn + h * Dn + d];
    wka[(size_t)c * Dn + d] = s / Hn;
    if (c == 0) {
      double t = 0.0;
      for (int h = 0; h < Hn; ++h) t += (double)bk[h * Dn + d];
      bka[d] = t / Hn;
    }
  }
}

__global__ __launch_bounds__(128) void metric_d_kernel(const float* __restrict__ x,
                                                       const double* __restrict__ sd,
                                                       const float* __restrict__ g,
                                                       const float* __restrict__ b,
                                                       const double* __restrict__ wka,
                                                       const double* __restrict__ bka,
                                                       double* __restrict__ mn) {
  int row = blockIdx.x;  // b*N + n
  __shared__ double as_[Cn];
  __shared__ double red[Dn];
  __shared__ double nrm;
  double mean = sd[2 * row], rstd = sd[2 * row + 1];
  const float* xr = x + (size_t)row * Cn;
  for (int c = threadIdx.x; c < Cn; c += 128)
    as_[c] = ((double)xr[c] - mean) * rstd * (double)g[c] + (double)b[c];
  __syncthreads();
  int d = threadIdx.x;
  double acc = 0.0;
  if (d < Dn) {
    for (int c = 0; c < Cn; ++c) acc += as_[c] * wka[(size_t)c * Dn + d];
    acc += bka[d];
    red[d] = acc * acc;
  }
  __syncthreads();
  if (threadIdx.x == 0) {
    double t = 0.0;
    for (int i = 0; i < Dn; ++i) t += red[i];
    nrm = 1.0 / sqrt(t > 0.0 ? t : 1e-300);
  }
  __syncthreads();
  if (d < Dn) mn[(size_t)row * Dn + d] = acc * nrm;
}

__global__ __launch_bounds__(128) void tome_score_kernel(const double* __restrict__ mn,
                                                         double* __restrict__ nmax,
                                                         int* __restrict__ nidx) {
  int blk = blockIdx.x;
  int i = blk % NAn;
  int b = blk / NAn;
  __shared__ double av[Dn];
  __shared__ double sv[128];
  __shared__ int si[128];
  int tid = threadIdx.x;
  if (tid < Dn) av[tid] = mn[((size_t)(b * Nn) + 2 * i) * Dn + tid];
  __syncthreads();
  double best = -1e300;
  int bi = 0;
  for (int c2 = tid; c2 < NBn; c2 += 128) {
    const double* bv = mn + ((size_t)(b * Nn) + 2 * c2 + 1) * Dn;
    double s = 0.0;
#pragma unroll 8
    for (int dd = 0; dd < Dn; ++dd) s += av[dd] * bv[dd];
    if (s > best) { best = s; bi = c2; }  // strict > keeps first occurrence
  }
  sv[tid] = best;
  si[tid] = bi;
  __syncthreads();
  if (tid == 0) {
    double bb = sv[0];
    int ii = si[0];
    for (int t2 = 1; t2 < 128; ++t2) {
      if (sv[t2] > bb || (sv[t2] == bb && si[t2] < ii)) { bb = sv[t2]; ii = si[t2]; }
    }
    nmax[b * NAn + i] = bb;
    nidx[b * NAn + i] = clampi(ii, 0, NBn - 1);
  }
}

__global__ __launch_bounds__(512) void tome_sort_kernel(const double* __restrict__ nmax,
                                                        const int* __restrict__ nidx,
                                                        int* __restrict__ unm,
                                                        int* __restrict__ srcI,
                                                        int* __restrict__ dstI,
                                                        float* __restrict__ cnt) {
  int b = blockIdx.x;
  __shared__ double v[NAn];
  __shared__ int eidx[NAn];
  __shared__ int dsts[Rn];
  int tid = threadIdx.x;
  for (int i = tid; i < NAn; i += blockDim.x) {
    v[i] = nmax[b * NAn + i];
    eidx[i] = i;  // defensive init
  }
  __syncthreads();
  for (int i = tid; i < NAn; i += blockDim.x) {
    double vi = v[i];
    int rank = 0;
    for (int j = 0; j < NAn; ++j) {
      double vj = v[j];
      rank += (vj > vi) || (vj == vi && j < i);  // stable descending
    }
    eidx[clampi(rank, 0, NAn - 1)] = i;
  }
  __syncthreads();
  for (int r2 = tid; r2 < NAn; r2 += blockDim.x) {
    if (r2 >= Rn) unm[(size_t)b * UNMn + (r2 - Rn)] = clampi(eidx[r2], 0, NAn - 1);
  }
  if (tid < Rn) {
    int s = clampi(eidx[tid], 0, NAn - 1);
    srcI[b * Rn + tid] = s;
    int dd = clampi(nidx[b * NAn + s], 0, NBn - 1);
    dsts[tid] = dd;
    dstI[b * Rn + tid] = dd;
  }
  for (int j = tid; j < NBn; j += blockDim.x) cnt[(size_t)b * NBn + j] = 1.f;
  __syncthreads();
  if (tid == 0) {
    for (int r2 = 0; r2 < Rn; ++r2) cnt[(size_t)b * NBn + dsts[r2]] += 1.f;
  }
}

// -------- ToMe merge (fp32): [B,729,C] -> [B,706,C] --------
__global__ __launch_bounds__(256) void tome_merge_kernel(const float* __restrict__ h,
                                                         const int* __restrict__ unm,
                                                         const int* __restrict__ srcI,
                                                         const int* __restrict__ dstI,
                                                         const float* __restrict__ cnt,
                                                         float* __restrict__ mg) {
  int blk = blockIdx.x;
  int t = blk % NMn;
  int b = blk / NMn;
  __shared__ int s_src[Rn], s_dst[Rn];
  if (threadIdx.x < Rn) {
    s_src[threadIdx.x] = clampi(srcI[b * Rn + threadIdx.x], 0, NAn - 1);
    s_dst[threadIdx.x] = clampi(dstI[b * Rn + threadIdx.x], 0, NBn - 1);
  }
  __syncthreads();
  if (t < UNMn) {
    int tok = clampi(2 * clampi(unm[(size_t)b * UNMn + t], 0, NAn - 1), 0, Nn - 1);
    for (int c = threadIdx.x; c < Cn; c += 256)
      mg[((size_t)(b * NMn + t)) * Cn + c] = h[((size_t)(b * Nn + tok)) * Cn + c];
  } else {
    int j = t - UNMn;
    int tok = 2 * j + 1;
    float inv = 1.f / cnt[b * NBn + j];
    for (int c = threadIdx.x; c < Cn; c += 256) {
      float vsum = h[((size_t)(b * Nn + tok)) * Cn + c];
      for (int r2 = 0; r2 < Rn; ++r2)
        if (s_dst[r2] == j) vsum += h[((size_t)(b * Nn + 2 * s_src[r2])) * Cn + c];
      mg[((size_t)(b * NMn + t)) * Cn + c] = vsum * inv;
    }
  }
}

inline int cdiv(int a, int b) { return (a + b - 1) / b; }

}  // namespace

extern "C" void kernel_launch(void* const* d_in, const int* in_sizes, int n_in,
                              void* d_out, int out_size, void* d_ws, size_t ws_size,
                              hipStream_t stream) {
  const float* hidden = (const float*)d_in[0];
  const float* mask   = (const float*)d_in[1];
  const float* wq = (const float*)d_in[2];
  const float* bq = (const float*)d_in[3];
  const float* wk = (const float*)d_in[4];
  const float* bk = (const float*)d_in[5];
  const float* wv = (const float*)d_in[6];
  const float* bv = (const float*)d_in[7];
  const float* wo = (const float*)d_in[8];
  const float* bo = (const float*)d_in[9];
  const float* ln1w = (const float*)d_in[10];
  const float* ln1b = (const float*)d_in[11];
  const float* ln2w = (const float*)d_in[12];
  const float* ln2b = (const float*)d_in[13];
  const float* fc1w = (const float*)d_in[14];
  const float* fc1b = (const float*)d_in[15];
  const float* fc2w = (const float*)d_in[16];
  const float* fc2b = (const float*)d_in[17];
  float* out = (float*)d_out;
  (void)in_sizes; (void)n_in; (void)out_size; (void)ws_size;

  char* ws = (char*)d_ws;
  size_t off = 0;
  auto alloc = [&](size_t nbytes) -> void* {
    void* p = ws + off;
    off += (nbytes + 255) & ~(size_t)255;
    return p;
  };
  int rows = Bn * Nn;    // 5832
  int mrows = Bn * NMn;  // 5648
  size_t bnc = (size_t)rows * Cn;
  bf16* wqT = (bf16*)alloc((size_t)Cn * Cn * 2);
  bf16* wkT = (bf16*)alloc((size_t)Cn * Cn * 2);
  bf16* wvT = (bf16*)alloc((size_t)Cn * Cn * 2);
  bf16* woT = (bf16*)alloc((size_t)Cn * Cn * 2);
  bf16* fc1T = (bf16*)alloc((size_t)Fn * Cn * 2);
  bf16* fc2T = (bf16*)alloc((size_t)Cn * Fn * 2);
  bf16* xlnB = (bf16*)alloc(bnc * 2);             // LN1 out; later overlaid by mg (with qb)
  bf16* qb = (bf16*)alloc(bnc * 2);               // q -> attn-out (in-place)
  bf16* kb = (bf16*)alloc(bnc * 2);               // k; later overlaid by hbuf (with vb)
  bf16* vb = (bf16*)alloc(bnc * 2);               // v
  bf16* h2B = (bf16*)alloc((size_t)mrows * Cn * 2);
  constexpr int CHUNK = 2824;                     // mrows/2
  bf16* ffnB = (bf16*)alloc((size_t)CHUNK * Fn * 2);
  double* mnD = (double*)alloc((size_t)rows * Dn * 8);
  double* wkavgD = (double*)alloc((size_t)Cn * Dn * 8);
  double* bkavgD = (double*)alloc((size_t)Dn * 8);
  float* stats1f = (float*)alloc((size_t)rows * 2 * 4);
  double* stats1d = (double*)alloc((size_t)rows * 2 * 8);
  float* stats2f = (float*)alloc((size_t)mrows * 2 * 4);
  double* nmaxD = (double*)alloc((size_t)Bn * NAn * 8);
  int* nidx = (int*)alloc((size_t)Bn * NAn * 4);
  int* unm  = (int*)alloc((size_t)Bn * UNMn * 4);
  int* srcI = (int*)alloc((size_t)Bn * Rn * 4);
  int* dstI = (int*)alloc((size_t)Bn * Rn * 4);
  float* cnt = (float*)alloc((size_t)Bn * NBn * 4);
  float* hbuf = (float*)kb;   // overlays kb+vb (dead after attn)
  float* mg   = (float*)xlnB; // overlays xlnB+qb (dead after QKV / wo-gemm)

  // 0. Weight transpose+convert to bf16 [N][K]
  wconv_kernel<<<dim3(cdiv(Cn, 32), cdiv(Cn, 32)), 256, 0, stream>>>(wq, wqT, Cn, Cn);
  wconv_kernel<<<dim3(cdiv(Cn, 32), cdiv(Cn, 32)), 256, 0, stream>>>(wk, wkT, Cn, Cn);
  wconv_kernel<<<dim3(cdiv(Cn, 32), cdiv(Cn, 32)), 256, 0, stream>>>(wv, wvT, Cn, Cn);
  wconv_kernel<<<dim3(cdiv(Cn, 32), cdiv(Cn, 32)), 256, 0, stream>>>(wo, woT, Cn, Cn);
  wconv_kernel<<<dim3(cdiv(Fn, 32), cdiv(Cn, 32)), 256, 0, stream>>>(fc1w, fc1T, Cn, Fn);
  wconv_kernel<<<dim3(cdiv(Cn, 32), cdiv(Fn, 32)), 256, 0, stream>>>(fc2w, fc2T, Fn, Cn);

  // 1. LN1 stats (fp32 + fp64)
  ln_stats_kernel<<<rows, 256, 0, stream>>>(hidden, stats1f, stats1d, rows);

  // 2. Decision path, all fp64 (exactly matches np reference decisions)
  wkavg_kernel<<<Cn, 128, 0, stream>>>(wk, bk, wkavgD, bkavgD);
  metric_d_kernel<<<rows, 128, 0, stream>>>(hidden, stats1d, ln1w, ln1b, wkavgD, bkavgD, mnD);
  tome_score_kernel<<<Bn * NAn, 128, 0, stream>>>(mnD, nmaxD, nidx);
  tome_sort_kernel<<<Bn, 512, 0, stream>>>(nmaxD, nidx, unm, srcI, dstI, cnt);

  // 3. LN1 apply -> bf16
  ln_apply_kernel<<<rows, 256, 0, stream>>>(hidden, stats1f, ln1w, ln1b, xlnB);

  // 4. QKV projections (bf16 MFMA)
  dim3 g1(cdiv(Cn, 128), cdiv(rows, 128));
  mfma_gemm<bf16><<<g1, 256, 0, stream>>>(xlnB, wqT, bq, nullptr, qb, rows, Cn, Cn, 0);
  mfma_gemm<bf16><<<g1, 256, 0, stream>>>(xlnB, wkT, bk, nullptr, kb, rows, Cn, Cn, 0);
  mfma_gemm<bf16><<<g1, 256, 0, stream>>>(xlnB, wvT, bv, nullptr, vb, rows, Cn, Cn, 0);

  // 5. MFMA flash attention (in-place over q)
  attn_mfma_kernel<<<Bn * Hn * NQT2, 256, 0, stream>>>(qb, kb, vb, mask);

  // 6. Out-proj + residual(hidden) -> hbuf fp32 (overlays kb+vb)
  mfma_gemm<float><<<g1, 256, 0, stream>>>(qb, woT, bo, hidden, hbuf, rows, Cn, Cn, 0);

  // 7. ToMe merge -> mg fp32 (overlays xlnB+qb)
  tome_merge_kernel<<<Bn * NMn, 256, 0, stream>>>(hbuf, unm, srcI, dstI, cnt, mg);

  // 8. LN2 stats + apply -> h2B bf16
  ln_stats_kernel<<<mrows, 256, 0, stream>>>(mg, stats2f, (double*)nullptr, mrows);
  ln_apply_kernel<<<mrows, 256, 0, stream>>>(mg, stats2f, ln2w, ln2b, h2B);

  // 9. MLP (bf16 MFMA), 2 chunks; fc2 adds resid(mg) and writes fp32 d_out
  for (int c0 = 0; c0 < mrows; c0 += CHUNK) {
    int m = (mrows - c0 < CHUNK) ? (mrows - c0) : CHUNK;
    dim3 gf1(cdiv(Fn, 128), cdiv(m, 128));
    mfma_gemm<bf16><<<gf1, 256, 0, stream>>>(h2B + (size_t)c0 * Cn, fc1T, fc1b, nullptr,
                                             ffnB, m, Fn, Cn, 1);
    dim3 gf2(cdiv(Cn, 128), cdiv(m, 128));
    mfma_gemm<float><<<gf2, 256, 0, stream>>>(ffnB, fc2T, fc2b, mg + (size_t)c0 * Cn,
                                              out + (size_t)c0 * Cn, m, Cn, Fn, 0);
  }
}